// Round 1
// baseline (723.484 us; speedup 1.0000x reference)
//
#include <hip/hip_runtime.h>
#include <hip/hip_bf16.h>

#define D 64
#define N_NODES 50000
#define N_EDGES 800000

// ---------------- degree kernels ----------------
__global__ void zero_k(float* __restrict__ p, int n) {
    int i = blockIdx.x * blockDim.x + threadIdx.x;
    if (i < n) p[i] = 0.0f;
}

__global__ void count_k(const int* __restrict__ dst, float* __restrict__ deg, int E) {
    int i = blockIdx.x * blockDim.x + threadIdx.x;
    int stride = gridDim.x * blockDim.x;
    for (; i < E; i += stride) atomicAdd(&deg[dst[i]], 1.0f);
}

__global__ void dis_k(float* __restrict__ deg, int n) {
    int i = blockIdx.x * blockDim.x + threadIdx.x;
    if (i < n) deg[i] = rsqrtf(deg[i] + 1.0f);  // +1 self loop
}

// ---------------- GEMM: Hs = PRE(X) @ W * dis[row]; AGG init = Hs ----------------
// PRE==0: raw input.  PRE==1: x' = relu(x*dis[row] + bias[col]) (finishes previous layer).
template <int PRE>
__global__ void gemm_k(const float* __restrict__ X, const float* __restrict__ W,
                       const float* __restrict__ dis, const float* __restrict__ bias,
                       float* __restrict__ H, float* __restrict__ AGG, int N) {
    __shared__ float Ws[D * D];
    __shared__ float Xs[4][D];
    for (int i = threadIdx.x; i < D * D; i += blockDim.x) Ws[i] = W[i];
    __syncthreads();

    int r = threadIdx.x >> 6;   // 0..3 (row within block tile)
    int c = threadIdx.x & 63;   // output column

    for (int row0 = blockIdx.x * 4; row0 < N; row0 += gridDim.x * 4) {
        int row = row0 + r;
        if (row < N) {
            float v = X[(size_t)row * D + c];
            if (PRE == 1) v = fmaxf(fmaf(v, dis[row], bias[c]), 0.0f);
            Xs[r][c] = v;
        }
        __syncthreads();
        if (row < N) {
            float acc = 0.0f;
#pragma unroll
            for (int k = 0; k < D; ++k) acc = fmaf(Xs[r][k], Ws[k * D + c], acc);
            float hs = acc * dis[row];
            H[(size_t)row * D + c] = hs;     // gather source
            AGG[(size_t)row * D + c] = hs;   // agg init = self-loop term (pre-scale)
        }
        __syncthreads();
    }
}

// ---------------- edge scatter: AGG[dst] += Hs[src] ----------------
__global__ void scatter_k(const float* __restrict__ Hs, const int* __restrict__ src,
                          const int* __restrict__ dst, float* __restrict__ AGG, int E) {
    int wid = (blockIdx.x * blockDim.x + threadIdx.x) >> 6;
    int lane = threadIdx.x & 63;
    int nw = (gridDim.x * blockDim.x) >> 6;
    for (int e = wid; e < E; e += nw) {
        int s = src[e];
        int d = dst[e];
        float v = Hs[(size_t)s * D + lane];
        atomicAdd(&AGG[(size_t)d * D + lane], v);
    }
}

// ---------------- final projection: out[i] = relu(AGG*dis+b) . Wout + bout ----------------
__global__ void proj_k(const float* __restrict__ AGG, const float* __restrict__ dis,
                       const float* __restrict__ bias, const float* __restrict__ Wout,
                       const float* __restrict__ bout, float* __restrict__ out, int N) {
    int wid = (blockIdx.x * blockDim.x + threadIdx.x) >> 6;
    int lane = threadIdx.x & 63;
    int nw = (gridDim.x * blockDim.x) >> 6;
    float wc = Wout[lane];
    float b = bout[0];
    for (int i = wid; i < N; i += nw) {
        float v = fmaxf(fmaf(AGG[(size_t)i * D + lane], dis[i], bias[lane]), 0.0f) * wc;
#pragma unroll
        for (int off = 32; off; off >>= 1) v += __shfl_down(v, off, 64);
        if (lane == 0) out[i] = v + b;
    }
}

extern "C" void kernel_launch(void* const* d_in, const int* in_sizes, int n_in,
                              void* d_out, int out_size, void* d_ws, size_t ws_size,
                              hipStream_t stream) {
    const float* x    = (const float*)d_in[0];
    const int*   ei   = (const int*)d_in[1];
    const float* W0   = (const float*)d_in[2];
    const float* b0   = (const float*)d_in[3];
    const float* W1   = (const float*)d_in[4];
    const float* b1   = (const float*)d_in[5];
    const float* W2   = (const float*)d_in[6];
    const float* b2   = (const float*)d_in[7];
    const float* Wout = (const float*)d_in[8];
    const float* bout = (const float*)d_in[9];
    float* out = (float*)d_out;

    const int N = N_NODES, E = N_EDGES;
    const int* src = ei;
    const int* dst = ei + E;

    char* ws = (char*)d_ws;
    float* dis  = (float*)(ws);                        // N floats
    float* bufA = (float*)(ws + (512ull << 10));       // N*D floats (Hs)
    float* bufB = (float*)(ws + (512ull << 10) + (13ull << 20));  // N*D floats (AGG)

    dim3 blk(256);
    dim3 gN((N + 255) / 256);
    dim3 gBig(2048);

    // degree -> deg_isqrt (in place)
    zero_k<<<gN, blk, 0, stream>>>(dis, N);
    count_k<<<gBig, blk, 0, stream>>>(dst, dis, E);
    dis_k<<<gN, blk, 0, stream>>>(dis, N);

    // layer 0: input = raw x
    gemm_k<0><<<gBig, blk, 0, stream>>>(x, W0, dis, nullptr, bufA, bufB, N);
    scatter_k<<<gBig, blk, 0, stream>>>(bufA, src, dst, bufB, E);

    // layer 1: input = relu(bufB*dis + b0)
    gemm_k<1><<<gBig, blk, 0, stream>>>(bufB, W1, dis, b0, bufA, bufB, N);
    scatter_k<<<gBig, blk, 0, stream>>>(bufA, src, dst, bufB, E);

    // layer 2: input = relu(bufB*dis + b1)
    gemm_k<1><<<gBig, blk, 0, stream>>>(bufB, W2, dis, b1, bufA, bufB, N);
    scatter_k<<<gBig, blk, 0, stream>>>(bufA, src, dst, bufB, E);

    // projection: input = relu(bufB*dis + b2)
    proj_k<<<gBig, blk, 0, stream>>>(bufB, dis, b2, Wout, bout, out, N);
}

// Round 2
// 498.833 us; speedup vs baseline: 1.4504x; 1.4504x over previous
//
#include <hip/hip_runtime.h>
#include <hip/hip_bf16.h>

#define D 64
#define N_NODES 50000
#define N_EDGES 800000
#define SCAN_T 1024

// ---------------- CSR build ----------------
__global__ void zero_i(int* __restrict__ p, int n) {
    int i = blockIdx.x * blockDim.x + threadIdx.x;
    if (i < n) p[i] = 0;
}

__global__ void hist_k(const int* __restrict__ dst, int* __restrict__ cnt, int E) {
    int i = blockIdx.x * blockDim.x + threadIdx.x;
    if (i < E) atomicAdd(&cnt[dst[i]], 1);
}

__global__ void dis_k(const int* __restrict__ cnt, float* __restrict__ dis, int n) {
    int i = blockIdx.x * blockDim.x + threadIdx.x;
    if (i < n) dis[i] = rsqrtf((float)cnt[i] + 1.0f);  // +1 self loop
}

// single-block exclusive scan over cnt -> off (N+1) and cursor (copy)
__global__ void scan_k(const int* __restrict__ cnt, int* __restrict__ off,
                       int* __restrict__ cursor, int N) {
    __shared__ int part[SCAN_T];
    int t = threadIdx.x;
    int chunk = (N + SCAN_T - 1) / SCAN_T;
    int lo = t * chunk;
    int hi = lo + chunk; if (hi > N) hi = N;
    int s = 0;
    for (int i = lo; i < hi; ++i) s += cnt[i];
    part[t] = s;
    __syncthreads();
    for (int d = 1; d < SCAN_T; d <<= 1) {
        int v = (t >= d) ? part[t - d] : 0;
        __syncthreads();
        part[t] += v;
        __syncthreads();
    }
    int run = (t == 0) ? 0 : part[t - 1];
    for (int i = lo; i < hi; ++i) {
        off[i] = run;
        cursor[i] = run;
        run += cnt[i];
    }
    if (t == SCAN_T - 1) off[N] = run;
}

__global__ void fill_k(const int* __restrict__ src, const int* __restrict__ dst,
                       int* __restrict__ cursor, int* __restrict__ esrc, int E) {
    int i = blockIdx.x * blockDim.x + threadIdx.x;
    if (i < E) {
        int pos = atomicAdd(&cursor[dst[i]], 1);
        esrc[pos] = src[i];
    }
}

// ---------------- GEMM: Hs = PRE(X) @ W * dis[row] ----------------
// PRE==0: raw input.  PRE==1: x' = relu(x*dis[row] + bias[col]) (finishes previous layer).
template <int PRE>
__global__ void gemm_k(const float* __restrict__ X, const float* __restrict__ W,
                       const float* __restrict__ dis, const float* __restrict__ bias,
                       float* __restrict__ H, int N) {
    __shared__ float Ws[D * D];
    __shared__ float Xs[4][D];
    for (int i = threadIdx.x; i < D * D; i += blockDim.x) Ws[i] = W[i];
    __syncthreads();

    int r = threadIdx.x >> 6;   // 0..3 (row within block tile)
    int c = threadIdx.x & 63;   // output column

    for (int row0 = blockIdx.x * 4; row0 < N; row0 += gridDim.x * 4) {
        int row = row0 + r;
        if (row < N) {
            float v = X[(size_t)row * D + c];
            if (PRE == 1) v = fmaxf(fmaf(v, dis[row], bias[c]), 0.0f);
            Xs[r][c] = v;
        }
        __syncthreads();
        if (row < N) {
            float acc = 0.0f;
#pragma unroll
            for (int k = 0; k < D; ++k) acc = fmaf(Xs[r][k], Ws[k * D + c], acc);
            H[(size_t)row * D + c] = acc * dis[row];  // gather source (self-loop handled in agg)
        }
        __syncthreads();
    }
}

// ---------------- segment gather: AGG[i] = Hs[i] + sum_{j in CSR row i} Hs[esrc[j]] ----------------
__global__ void agg_k(const float* __restrict__ Hs, const int* __restrict__ off,
                      const int* __restrict__ esrc, float* __restrict__ AGG, int N) {
    int wid = (blockIdx.x * blockDim.x + threadIdx.x) >> 6;
    int lane = threadIdx.x & 63;
    if (wid >= N) return;
    int beg = off[wid], end = off[wid + 1];
    float acc = Hs[(size_t)wid * D + lane];  // self-loop term (dis factored out)
    int j = beg;
    for (; j + 1 < end; j += 2) {
        int s0 = esrc[j], s1 = esrc[j + 1];
        float v0 = Hs[(size_t)s0 * D + lane];
        float v1 = Hs[(size_t)s1 * D + lane];
        acc += v0;
        acc += v1;
    }
    if (j < end) acc += Hs[(size_t)esrc[j] * D + lane];
    AGG[(size_t)wid * D + lane] = acc;
}

// ---------------- final projection: out[i] = relu(AGG*dis+b) . Wout + bout ----------------
__global__ void proj_k(const float* __restrict__ AGG, const float* __restrict__ dis,
                       const float* __restrict__ bias, const float* __restrict__ Wout,
                       const float* __restrict__ bout, float* __restrict__ out, int N) {
    int wid = (blockIdx.x * blockDim.x + threadIdx.x) >> 6;
    int lane = threadIdx.x & 63;
    if (wid >= N) return;
    float wc = Wout[lane];
    float b = bout[0];
    float v = fmaxf(fmaf(AGG[(size_t)wid * D + lane], dis[wid], bias[lane]), 0.0f) * wc;
#pragma unroll
    for (int off = 32; off; off >>= 1) v += __shfl_down(v, off, 64);
    if (lane == 0) out[wid] = v + b;
}

extern "C" void kernel_launch(void* const* d_in, const int* in_sizes, int n_in,
                              void* d_out, int out_size, void* d_ws, size_t ws_size,
                              hipStream_t stream) {
    const float* x    = (const float*)d_in[0];
    const int*   ei   = (const int*)d_in[1];
    const float* W0   = (const float*)d_in[2];
    const float* b0   = (const float*)d_in[3];
    const float* W1   = (const float*)d_in[4];
    const float* b1   = (const float*)d_in[5];
    const float* W2   = (const float*)d_in[6];
    const float* b2   = (const float*)d_in[7];
    const float* Wout = (const float*)d_in[8];
    const float* bout = (const float*)d_in[9];
    float* out = (float*)d_out;

    const int N = N_NODES, E = N_EDGES;
    const int* src = ei;
    const int* dst = ei + E;

    char* ws = (char*)d_ws;
    int*   cnt    = (int*)(ws);                   // N ints
    int*   off    = (int*)(ws + (256u << 10));    // N+1 ints
    int*   cursor = (int*)(ws + (512u << 10));    // N ints
    float* dis    = (float*)(ws + (768u << 10));  // N floats
    int*   esrc   = (int*)(ws + (1u << 20));      // E ints (3.2 MB)
    float* bufA   = (float*)(ws + (5u << 20));    // N*D floats (12.8 MB) - Hs
    float* bufB   = (float*)(ws + (18u << 20));   // N*D floats (12.8 MB) - AGG

    dim3 blk(256);
    dim3 gN((N + 255) / 256);      // 196
    dim3 gE((E + 255) / 256);      // 3125
    dim3 gAgg((N * 64 + 255) / 256);  // one wave per node: 12500
    dim3 gGemm(2048);

    // ---- degree + CSR build ----
    zero_i<<<gN, blk, 0, stream>>>(cnt, N);
    hist_k<<<gE, blk, 0, stream>>>(dst, cnt, E);
    dis_k<<<gN, blk, 0, stream>>>(cnt, dis, N);
    scan_k<<<1, SCAN_T, 0, stream>>>(cnt, off, cursor, N);
    fill_k<<<gE, blk, 0, stream>>>(src, dst, cursor, esrc, E);

    // ---- layer 0: input = raw x ----
    gemm_k<0><<<gGemm, blk, 0, stream>>>(x, W0, dis, nullptr, bufA, N);
    agg_k<<<gAgg, blk, 0, stream>>>(bufA, off, esrc, bufB, N);

    // ---- layer 1: input = relu(bufB*dis + b0) ----
    gemm_k<1><<<gGemm, blk, 0, stream>>>(bufB, W1, dis, b0, bufA, N);
    agg_k<<<gAgg, blk, 0, stream>>>(bufA, off, esrc, bufB, N);

    // ---- layer 2: input = relu(bufB*dis + b1) ----
    gemm_k<1><<<gGemm, blk, 0, stream>>>(bufB, W2, dis, b1, bufA, N);
    agg_k<<<gAgg, blk, 0, stream>>>(bufA, off, esrc, bufB, N);

    // ---- projection ----
    proj_k<<<gAgg, blk, 0, stream>>>(bufB, dis, b2, Wout, bout, out, N);
}

// Round 5
// 353.883 us; speedup vs baseline: 2.0444x; 1.4096x over previous
//
#include <hip/hip_runtime.h>
#include <hip/hip_bf16.h>

#define D 64
#define N_NODES 50000
#define N_EDGES 800000

// ---------------- CSR build ----------------
__global__ void zero_i(int* __restrict__ p, int n) {
    int i = blockIdx.x * blockDim.x + threadIdx.x;
    if (i < n) p[i] = 0;
}

__global__ void hist_k(const int* __restrict__ dst, int* __restrict__ cnt, int E) {
    int i = blockIdx.x * blockDim.x + threadIdx.x;
    if (i < E) atomicAdd(&cnt[dst[i]], 1);
}

__global__ void dis_k(const int* __restrict__ cnt, float* __restrict__ dis, int n) {
    int i = blockIdx.x * blockDim.x + threadIdx.x;
    if (i < n) dis[i] = rsqrtf((float)cnt[i] + 1.0f);  // +1 self loop
}

// ---- hierarchical exclusive scan: scan1 (per-block) -> scan2 (block sums) -> scan3 (add) ----
__global__ void scan1_k(const int* __restrict__ cnt, int* __restrict__ off,
                        int* __restrict__ bsum, int N) {
    __shared__ int sh[256];
    int t = threadIdx.x;
    int i = blockIdx.x * 256 + t;
    int v = (i < N) ? cnt[i] : 0;
    sh[t] = v;
    __syncthreads();
#pragma unroll
    for (int d = 1; d < 256; d <<= 1) {
        int u = (t >= d) ? sh[t - d] : 0;
        __syncthreads();
        sh[t] += u;
        __syncthreads();
    }
    if (i < N) off[i] = sh[t] - v;           // exclusive within block
    if (t == 255) bsum[blockIdx.x] = sh[255];
}

__global__ void scan2_k(int* __restrict__ bsum, int nb) {  // in-place exclusive scan, nb<=256
    __shared__ int sh[256];
    int t = threadIdx.x;
    int v = (t < nb) ? bsum[t] : 0;
    sh[t] = v;
    __syncthreads();
#pragma unroll
    for (int d = 1; d < 256; d <<= 1) {
        int u = (t >= d) ? sh[t - d] : 0;
        __syncthreads();
        sh[t] += u;
        __syncthreads();
    }
    if (t < nb) bsum[t] = sh[t] - v;
}

__global__ void scan3_k(int* __restrict__ off, const int* __restrict__ bsum,
                        int* __restrict__ cursor, int N, int E) {
    int i = blockIdx.x * 256 + threadIdx.x;
    if (i < N) {
        int o = off[i] + bsum[blockIdx.x];
        off[i] = o;
        cursor[i] = o;
    }
    if (i == 0) off[N] = E;
}

__global__ void fill_k(const int* __restrict__ src, const int* __restrict__ dst,
                       int* __restrict__ cursor, int* __restrict__ esrc, int E) {
    int i = blockIdx.x * blockDim.x + threadIdx.x;
    if (i < E) {
        int pos = atomicAdd(&cursor[dst[i]], 1);
        esrc[pos] = src[i];
    }
}

// ---------------- GEMM: Hs = PRE(X) @ W * dis[row] ----------------
template <int PRE>
__global__ void gemm_k(const float* __restrict__ X, const float* __restrict__ W,
                       const float* __restrict__ dis, const float* __restrict__ bias,
                       float* __restrict__ H, int N) {
    __shared__ float Ws[D * D];
    __shared__ float Xs[4][D];
    for (int i = threadIdx.x; i < D * D; i += blockDim.x) Ws[i] = W[i];
    __syncthreads();

    int r = threadIdx.x >> 6;   // 0..3 (row within block tile)
    int c = threadIdx.x & 63;   // output column

    for (int row0 = blockIdx.x * 4; row0 < N; row0 += gridDim.x * 4) {
        int row = row0 + r;
        if (row < N) {
            float v = X[(size_t)row * D + c];
            if (PRE == 1) v = fmaxf(fmaf(v, dis[row], bias[c]), 0.0f);
            Xs[r][c] = v;
        }
        __syncthreads();
        if (row < N) {
            float acc = 0.0f;
#pragma unroll
            for (int k = 0; k < D; ++k) acc = fmaf(Xs[r][k], Ws[k * D + c], acc);
            H[(size_t)row * D + c] = acc * dis[row];  // self-loop handled in agg
        }
        __syncthreads();
    }
}

// ---------------- segment gather (float4): AGG[i] = Hs[i] + sum_{j in row i} Hs[esrc[j]] ----------------
// wave = 4 edge slots x 16 lanes; lane loads 16B chunk; cross-slot shfl reduce.
__global__ void agg_k(const float4* __restrict__ Hs4, const int* __restrict__ off,
                      const int* __restrict__ esrc, float4* __restrict__ AGG4, int N) {
    int wid = (blockIdx.x * blockDim.x + threadIdx.x) >> 6;
    int lane = threadIdx.x & 63;
    if (wid >= N) return;
    int grp = lane >> 4;    // edge slot 0..3
    int l16 = lane & 15;    // float4 chunk within row
    int beg = off[wid], end = off[wid + 1];

    float4 acc = make_float4(0.f, 0.f, 0.f, 0.f);
    if (grp == 0) acc = Hs4[(size_t)wid * 16 + l16];  // self-loop term

    for (int j = beg + grp; j < end; j += 4) {
        int s = esrc[j];
        float4 v = Hs4[(size_t)s * 16 + l16];
        acc.x += v.x; acc.y += v.y; acc.z += v.z; acc.w += v.w;
    }
    // reduce across the 4 edge slots (lanes differing in bits 4,5)
#pragma unroll
    for (int m = 16; m <= 32; m <<= 1) {
        acc.x += __shfl_xor(acc.x, m, 64);
        acc.y += __shfl_xor(acc.y, m, 64);
        acc.z += __shfl_xor(acc.z, m, 64);
        acc.w += __shfl_xor(acc.w, m, 64);
    }
    if (grp == 0) AGG4[(size_t)wid * 16 + l16] = acc;
}

// ---------------- final projection ----------------
__global__ void proj_k(const float* __restrict__ AGG, const float* __restrict__ dis,
                       const float* __restrict__ bias, const float* __restrict__ Wout,
                       const float* __restrict__ bout, float* __restrict__ out, int N) {
    int wid = (blockIdx.x * blockDim.x + threadIdx.x) >> 6;
    int lane = threadIdx.x & 63;
    if (wid >= N) return;
    float wc = Wout[lane];
    float b = bout[0];
    float v = fmaxf(fmaf(AGG[(size_t)wid * D + lane], dis[wid], bias[lane]), 0.0f) * wc;
#pragma unroll
    for (int off = 32; off; off >>= 1) v += __shfl_down(v, off, 64);
    if (lane == 0) out[wid] = v + b;
}

extern "C" void kernel_launch(void* const* d_in, const int* in_sizes, int n_in,
                              void* d_out, int out_size, void* d_ws, size_t ws_size,
                              hipStream_t stream) {
    const float* x    = (const float*)d_in[0];
    const int*   ei   = (const int*)d_in[1];
    const float* W0   = (const float*)d_in[2];
    const float* b0   = (const float*)d_in[3];
    const float* W1   = (const float*)d_in[4];
    const float* b1   = (const float*)d_in[5];
    const float* W2   = (const float*)d_in[6];
    const float* b2   = (const float*)d_in[7];
    const float* Wout = (const float*)d_in[8];
    const float* bout = (const float*)d_in[9];
    float* out = (float*)d_out;

    const int N = N_NODES, E = N_EDGES;
    const int* src = ei;
    const int* dst = ei + E;

    // ws layout (byte offsets) — NO OVERLAPS:
    //   cnt    [0,       200000)
    //   off    [262144,  462148)   (N+1 ints)
    //   cursor [524288,  724288)
    //   dis    [786432,  986432)   (N floats, ends @986432)
    //   bsum   [1013760, 1014784)  (256 ints; 990 KiB — AFTER dis end, BEFORE esrc)
    //   esrc   [1048576, 4248576)  (E ints)
    //   bufA   [5 MiB,   +12.8 MB) (Hs)
    //   bufB   [18 MiB,  +12.8 MB) (AGG)
    char* ws = (char*)d_ws;
    int*   cnt    = (int*)(ws);
    int*   off    = (int*)(ws + (256u << 10));
    int*   cursor = (int*)(ws + (512u << 10));
    float* dis    = (float*)(ws + (768u << 10));
    int*   bsum   = (int*)(ws + (990u << 10));
    int*   esrc   = (int*)(ws + (1u << 20));
    float* bufA   = (float*)(ws + (5u << 20));
    float* bufB   = (float*)(ws + (18u << 20));

    dim3 blk(256);
    const int NB = (N + 255) / 256;   // 196
    dim3 gN(NB);
    dim3 gE((E + 255) / 256);         // 3125
    dim3 gAgg((N * 64 + 255) / 256);  // one wave per node: 12500
    dim3 gGemm(2048);

    // ---- degree + CSR build ----
    zero_i<<<gN, blk, 0, stream>>>(cnt, N);
    hist_k<<<gE, blk, 0, stream>>>(dst, cnt, E);
    dis_k<<<gN, blk, 0, stream>>>(cnt, dis, N);
    scan1_k<<<gN, blk, 0, stream>>>(cnt, off, bsum, N);
    scan2_k<<<1, blk, 0, stream>>>(bsum, NB);
    scan3_k<<<gN, blk, 0, stream>>>(off, bsum, cursor, N, E);
    fill_k<<<gE, blk, 0, stream>>>(src, dst, cursor, esrc, E);

    // ---- layer 0 ----
    gemm_k<0><<<gGemm, blk, 0, stream>>>(x, W0, dis, nullptr, bufA, N);
    agg_k<<<gAgg, blk, 0, stream>>>((const float4*)bufA, off, esrc, (float4*)bufB, N);

    // ---- layer 1 ----
    gemm_k<1><<<gGemm, blk, 0, stream>>>(bufB, W1, dis, b0, bufA, N);
    agg_k<<<gAgg, blk, 0, stream>>>((const float4*)bufA, off, esrc, (float4*)bufB, N);

    // ---- layer 2 ----
    gemm_k<1><<<gGemm, blk, 0, stream>>>(bufB, W2, dis, b1, bufA, N);
    agg_k<<<gAgg, blk, 0, stream>>>((const float4*)bufA, off, esrc, (float4*)bufB, N);

    // ---- projection ----
    proj_k<<<gAgg, blk, 0, stream>>>(bufB, dis, b2, Wout, bout, out, N);
}

// Round 6
// 345.903 us; speedup vs baseline: 2.0916x; 1.0231x over previous
//
#include <hip/hip_runtime.h>
#include <hip/hip_bf16.h>

#define D 64
#define N_NODES 50000
#define N_EDGES 800000

// ---------------- CSR build ----------------
__global__ void hist_k(const int* __restrict__ dst, int* __restrict__ cnt, int E) {
    int i = blockIdx.x * blockDim.x + threadIdx.x;
    if (i < E) atomicAdd(&cnt[dst[i]], 1);
}

// per-block scan of cnt -> off (exclusive within block), block sums; also dis = rsqrt(cnt+1)
__global__ void scan1_k(const int* __restrict__ cnt, int* __restrict__ off,
                        int* __restrict__ bsum, float* __restrict__ dis, int N) {
    __shared__ int sh[256];
    int t = threadIdx.x;
    int i = blockIdx.x * 256 + t;
    int v = (i < N) ? cnt[i] : 0;
    sh[t] = v;
    __syncthreads();
#pragma unroll
    for (int d = 1; d < 256; d <<= 1) {
        int u = (t >= d) ? sh[t - d] : 0;
        __syncthreads();
        sh[t] += u;
        __syncthreads();
    }
    if (i < N) {
        off[i] = sh[t] - v;              // exclusive within block
        dis[i] = rsqrtf((float)v + 1.0f); // +1 self loop
    }
    if (t == 255) bsum[blockIdx.x] = sh[255];
}

__global__ void scan2_k(int* __restrict__ bsum, int nb) {  // in-place exclusive scan, nb<=256
    __shared__ int sh[256];
    int t = threadIdx.x;
    int v = (t < nb) ? bsum[t] : 0;
    sh[t] = v;
    __syncthreads();
#pragma unroll
    for (int d = 1; d < 256; d <<= 1) {
        int u = (t >= d) ? sh[t - d] : 0;
        __syncthreads();
        sh[t] += u;
        __syncthreads();
    }
    if (t < nb) bsum[t] = sh[t] - v;
}

__global__ void scan3_k(int* __restrict__ off, const int* __restrict__ bsum,
                        int* __restrict__ cursor, int N, int E) {
    int i = blockIdx.x * 256 + threadIdx.x;
    if (i < N) {
        int o = off[i] + bsum[blockIdx.x];
        off[i] = o;
        cursor[i] = o;
    }
    if (i == 0) off[N] = E;
}

// ---------------- fused: CSR fill (blocks >= gemmBlocks) || gemm0 (blocks < gemmBlocks) ----------------
// gemm0: Hs0 = (x @ W0) * dis[row]
__global__ void fused0_k(const float* __restrict__ X, const float* __restrict__ W,
                         const float* __restrict__ dis, float* __restrict__ H,
                         const int* __restrict__ src, const int* __restrict__ dst,
                         int* __restrict__ cursor, int* __restrict__ esrc,
                         int N, int E, int gemmBlocks) {
    __shared__ float Ws[D * D];
    __shared__ float Xs[4][D];
    int bid = blockIdx.x;
    if (bid < gemmBlocks) {
        for (int i = threadIdx.x; i < D * D; i += blockDim.x) Ws[i] = W[i];
        __syncthreads();
        int r = threadIdx.x >> 6;
        int c = threadIdx.x & 63;
        for (int row0 = bid * 4; row0 < N; row0 += gemmBlocks * 4) {
            int row = row0 + r;
            if (row < N) Xs[r][c] = X[(size_t)row * D + c];
            __syncthreads();
            if (row < N) {
                float acc = 0.0f;
#pragma unroll
                for (int k = 0; k < D; ++k) acc = fmaf(Xs[r][k], Ws[k * D + c], acc);
                H[(size_t)row * D + c] = acc * dis[row];
            }
            __syncthreads();
        }
    } else {
        int fb = bid - gemmBlocks;
        int nfb = gridDim.x - gemmBlocks;
        for (int i = fb * 256 + threadIdx.x; i < E; i += nfb * 256) {
            int pos = atomicAdd(&cursor[dst[i]], 1);
            esrc[pos] = src[i];
        }
    }
}

// ---------------- fused layer: gather + activation + next GEMM (or final projection) ----------------
// One wave per node. Input Hs (pre-scaled by dis[src]).
//   agg  = Hs[i] + sum_{j in CSR row i} Hs[esrc[j]]
//   h    = relu(agg * dis[i] + bias)
//   !FINAL: Hs_next[i][c] = (h @ W)[c] * dis[i]
//   FINAL : out[i] = h . Wout + bout
template <int FINAL>
__global__ void layer_k(const float4* __restrict__ Hs4, const int* __restrict__ off,
                        const int* __restrict__ esrc, const float* __restrict__ dis,
                        const float* __restrict__ bias, const float* __restrict__ W,
                        const float* __restrict__ bout, float* __restrict__ outp, int N) {
    int wid = (blockIdx.x * blockDim.x + threadIdx.x) >> 6;
    int lane = threadIdx.x & 63;
    int grp = lane >> 4;     // edge slot 0..3
    int l16 = lane & 15;     // float4 chunk within row
    int c = lane;            // output column (GEMM role)

    // lane-resident weight column (64 VGPRs), loaded coalesced: W[k*64+c]
    float Wc[64];
    if (!FINAL) {
#pragma unroll
        for (int k = 0; k < 64; ++k) Wc[k] = W[k * 64 + c];
    }
    float4 b4 = ((const float4*)bias)[l16];

    if (wid >= N) return;

    int beg = off[wid], end = off[wid + 1];
    float4 acc = make_float4(0.f, 0.f, 0.f, 0.f);
    if (grp == 0) acc = Hs4[(size_t)wid * 16 + l16];  // self-loop term

    int j = beg + grp;
    // unrolled: 16 edges (4 per slot) in flight per iteration
    for (; j + 12 < end; j += 16) {
        int s0 = esrc[j], s1 = esrc[j + 4], s2 = esrc[j + 8], s3 = esrc[j + 12];
        float4 v0 = Hs4[(size_t)s0 * 16 + l16];
        float4 v1 = Hs4[(size_t)s1 * 16 + l16];
        float4 v2 = Hs4[(size_t)s2 * 16 + l16];
        float4 v3 = Hs4[(size_t)s3 * 16 + l16];
        acc.x += (v0.x + v1.x) + (v2.x + v3.x);
        acc.y += (v0.y + v1.y) + (v2.y + v3.y);
        acc.z += (v0.z + v1.z) + (v2.z + v3.z);
        acc.w += (v0.w + v1.w) + (v2.w + v3.w);
    }
    for (; j < end; j += 4) {
        int s = esrc[j];
        float4 v = Hs4[(size_t)s * 16 + l16];
        acc.x += v.x; acc.y += v.y; acc.z += v.z; acc.w += v.w;
    }
    // reduce across the 4 edge slots (lane bits 4,5)
#pragma unroll
    for (int m = 16; m <= 32; m <<= 1) {
        acc.x += __shfl_xor(acc.x, m, 64);
        acc.y += __shfl_xor(acc.y, m, 64);
        acc.z += __shfl_xor(acc.z, m, 64);
        acc.w += __shfl_xor(acc.w, m, 64);
    }
    // activation: h = relu(agg * dis[i] + b)
    float dv = dis[wid];
    float4 h4;
    h4.x = fmaxf(fmaf(acc.x, dv, b4.x), 0.f);
    h4.y = fmaxf(fmaf(acc.y, dv, b4.y), 0.f);
    h4.z = fmaxf(fmaf(acc.z, dv, b4.z), 0.f);
    h4.w = fmaxf(fmaf(acc.w, dv, b4.w), 0.f);

    if (FINAL) {
        float4 w4 = ((const float4*)W)[l16];  // Wout chunk
        float p = h4.x * w4.x + h4.y * w4.y + h4.z * w4.z + h4.w * w4.w;
        // sum the 16 chunks (lane bits 0..3); grps hold identical copies
        p += __shfl_xor(p, 1, 64);
        p += __shfl_xor(p, 2, 64);
        p += __shfl_xor(p, 4, 64);
        p += __shfl_xor(p, 8, 64);
        if (lane == 0) outp[wid] = p + bout[0];
    } else {
        // GEMM row: out[c] = sum_k h[k] * W[k][c]; h[k] broadcast from lane k/4
        float o = 0.f;
#pragma unroll
        for (int ch = 0; ch < 16; ++ch) {
            float hx = __shfl(h4.x, ch, 64);
            float hy = __shfl(h4.y, ch, 64);
            float hz = __shfl(h4.z, ch, 64);
            float hw = __shfl(h4.w, ch, 64);
            o = fmaf(hx, Wc[4 * ch + 0], o);
            o = fmaf(hy, Wc[4 * ch + 1], o);
            o = fmaf(hz, Wc[4 * ch + 2], o);
            o = fmaf(hw, Wc[4 * ch + 3], o);
        }
        outp[(size_t)wid * 64 + c] = o * dv;  // pre-scale for next layer's gather
    }
}

extern "C" void kernel_launch(void* const* d_in, const int* in_sizes, int n_in,
                              void* d_out, int out_size, void* d_ws, size_t ws_size,
                              hipStream_t stream) {
    const float* x    = (const float*)d_in[0];
    const int*   ei   = (const int*)d_in[1];
    const float* W0   = (const float*)d_in[2];
    const float* b0   = (const float*)d_in[3];
    const float* W1   = (const float*)d_in[4];
    const float* b1   = (const float*)d_in[5];
    const float* W2   = (const float*)d_in[6];
    const float* b2   = (const float*)d_in[7];
    const float* Wout = (const float*)d_in[8];
    const float* bout = (const float*)d_in[9];
    float* out = (float*)d_out;

    const int N = N_NODES, E = N_EDGES;
    const int* src = ei;
    const int* dst = ei + E;

    // ws layout (byte offsets) — verified no overlaps:
    //   cnt    [0,       200000)
    //   off    [262144,  462148)   (N+1 ints)
    //   cursor [524288,  724288)
    //   dis    [786432,  986432)
    //   bsum   [1013760, 1014784)  (990 KiB)
    //   esrc   [1048576, 4248576)
    //   bufA   [5 MiB,   +12.8 MB)
    //   bufB   [18 MiB,  +12.8 MB)
    char* ws = (char*)d_ws;
    int*   cnt    = (int*)(ws);
    int*   off    = (int*)(ws + (256u << 10));
    int*   cursor = (int*)(ws + (512u << 10));
    float* dis    = (float*)(ws + (768u << 10));
    int*   bsum   = (int*)(ws + (990u << 10));
    int*   esrc   = (int*)(ws + (1u << 20));
    float* bufA   = (float*)(ws + (5u << 20));
    float* bufB   = (float*)(ws + (18u << 20));

    dim3 blk(256);
    const int NB = (N + 255) / 256;   // 196
    dim3 gN(NB);
    dim3 gE((E + 255) / 256);         // 3125
    dim3 gWave((N * 64 + 255) / 256); // one wave per node: 12500 blocks
    const int GEMM_BLOCKS = 2048;
    const int FILL_BLOCKS = 1024;

    // ---- degree + CSR build ----
    hipMemsetAsync(cnt, 0, (size_t)N * sizeof(int), stream);
    hist_k<<<gE, blk, 0, stream>>>(dst, cnt, E);
    scan1_k<<<gN, blk, 0, stream>>>(cnt, off, bsum, dis, N);
    scan2_k<<<1, blk, 0, stream>>>(bsum, NB);
    scan3_k<<<gN, blk, 0, stream>>>(off, bsum, cursor, N, E);

    // ---- CSR fill || layer-0 GEMM (independent) ----
    fused0_k<<<dim3(GEMM_BLOCKS + FILL_BLOCKS), blk, 0, stream>>>(
        x, W0, dis, bufA, src, dst, cursor, esrc, N, E, GEMM_BLOCKS);

    // ---- fused layers: gather + relu(bias,dis) + next GEMM ----
    layer_k<0><<<gWave, blk, 0, stream>>>((const float4*)bufA, off, esrc, dis,
                                          b0, W1, nullptr, bufB, N);
    layer_k<0><<<gWave, blk, 0, stream>>>((const float4*)bufB, off, esrc, dis,
                                          b1, W2, nullptr, bufA, N);
    // ---- final: gather + relu + projection ----
    layer_k<1><<<gWave, blk, 0, stream>>>((const float4*)bufA, off, esrc, dis,
                                          b2, Wout, bout, out, N);
}